// Round 3
// baseline (1592.789 us; speedup 1.0000x reference)
//
#include <hip/hip_runtime.h>
#include <cstdint>
#include <cstddef>

// Problem constants (B=4, S=2048 -> T=8192 tokens)
#define T_TOK 8192
#define H_DIM 1024
#define F_DIM 3584
#define E_NUM 8
#define NASG (T_TOK * 2)     // 16384 assignments
#define NBLK 64              // scatter/hist blocks (64*256 = NASG)
#define MAX_ROWS 17408       // 2T assignments + per-expert pad to 128
#define MAX_TILES 136        // ceil-sum of per-expert tiles, worst case

typedef __bf16 bf16_t;
typedef bf16_t bf16x8 __attribute__((ext_vector_type(8)));
typedef bf16_t bf16x4 __attribute__((ext_vector_type(4)));
typedef float floatx4 __attribute__((ext_vector_type(4)));

typedef const __attribute__((address_space(1))) void* gas_ptr;
typedef __attribute__((address_space(3))) void* las_ptr;

// async global->LDS, 16B per lane. LDS dest = wave-uniform base + lane*16;
// global address is per-lane (gather OK).
__device__ __forceinline__ void async_copy16(const void* g, void* l) {
    __builtin_amdgcn_global_load_lds((gas_ptr)g, (las_ptr)l, 16, 0, 0);
}

// ---------------- elementwise fp32 -> bf16 cast (4 elems/thread) ----------------
__global__ void cast_f32_to_bf16(const float* __restrict__ in, bf16_t* __restrict__ out, int n4) {
    int i = blockIdx.x * blockDim.x + threadIdx.x;
    if (i < n4) {
        const float4 v = ((const float4*)in)[i];
        bf16x4 o;
        o[0] = (bf16_t)v.x; o[1] = (bf16_t)v.y; o[2] = (bf16_t)v.z; o[3] = (bf16_t)v.w;
        ((bf16x4*)out)[i] = o;
    }
}

// ---------------- w2 [E,F,H] fp32 -> w2t [E,H,F] bf16 (tiled transpose) ----------------
__global__ void transpose_cast_w2(const float* __restrict__ W2, bf16_t* __restrict__ W2T) {
    __shared__ bf16_t tile[32][34];
    const int e = blockIdx.z;
    const int f0 = blockIdx.x * 32;
    const int h0 = blockIdx.y * 32;
    const float* src = W2 + (size_t)e * F_DIM * H_DIM;
    bf16_t* dst = W2T + (size_t)e * H_DIM * F_DIM;
    const int tx = threadIdx.x;  // 0..31
    const int ty = threadIdx.y;  // 0..7
#pragma unroll
    for (int r = 0; r < 32; r += 8)
        tile[ty + r][tx] = (bf16_t)src[(size_t)(f0 + ty + r) * H_DIM + (h0 + tx)];
    __syncthreads();
#pragma unroll
    for (int r = 0; r < 32; r += 8)
        dst[(size_t)(h0 + ty + r) * F_DIM + (f0 + tx)] = tile[tx][ty + r];
}

// ---------------- router (+ fused x cast): top-2, renorm; writes xb bf16 ----------------
__global__ void router_kernel(const float* __restrict__ X, const float* __restrict__ RW,
                              int* __restrict__ tok_e, float* __restrict__ tok_w,
                              bf16_t* __restrict__ xb) {
    const int lane = threadIdx.x & 63;
    const int wave = threadIdx.x >> 6;
    const int t = blockIdx.x * 4 + wave;
    const float* xp = X + (size_t)t * H_DIM;
    float xr[16];
#pragma unroll
    for (int j = 0; j < 16; ++j) xr[j] = xp[j * 64 + lane];
    bf16_t* xo = xb + (size_t)t * H_DIM;
#pragma unroll
    for (int j = 0; j < 16; ++j) xo[j * 64 + lane] = (bf16_t)xr[j];
    float logits[E_NUM];
#pragma unroll
    for (int e = 0; e < E_NUM; ++e) {
        const float* rp = RW + e * H_DIM;
        float a = 0.f;
#pragma unroll
        for (int j = 0; j < 16; ++j) a += xr[j] * rp[j * 64 + lane];
#pragma unroll
        for (int s = 32; s; s >>= 1) a += __shfl_xor(a, s, 64);
        logits[e] = a;
    }
    if (lane == 0) {
        float mx = logits[0];
#pragma unroll
        for (int e = 1; e < E_NUM; ++e) mx = fmaxf(mx, logits[e]);
        float p[E_NUM], sum = 0.f;
#pragma unroll
        for (int e = 0; e < E_NUM; ++e) { p[e] = __expf(logits[e] - mx); sum += p[e]; }
#pragma unroll
        for (int e = 0; e < E_NUM; ++e) p[e] /= sum;
        int i0 = 0;
#pragma unroll
        for (int e = 1; e < E_NUM; ++e) if (p[e] > p[i0]) i0 = e;  // ties -> lowest idx
        int i1 = (i0 == 0) ? 1 : 0;
#pragma unroll
        for (int e = 0; e < E_NUM; ++e) if (e != i0 && p[e] > p[i1]) i1 = e;
        const float s2 = p[i0] + p[i1];
        tok_e[t * 2 + 0] = i0; tok_w[t * 2 + 0] = p[i0] / s2;
        tok_e[t * 2 + 1] = i1; tok_w[t * 2 + 1] = p[i1] / s2;
    }
}

// ---------------- deterministic counting sort: hist -> scan -> scatter ----------------
__global__ void hist_kernel(const int* __restrict__ tok_e, int* __restrict__ blk_cnt) {
    __shared__ int h[E_NUM];
    const int tid = threadIdx.x;
    if (tid < E_NUM) h[tid] = 0;
    __syncthreads();
    atomicAdd(&h[tok_e[blockIdx.x * 256 + tid]], 1);
    __syncthreads();
    if (tid < E_NUM) blk_cnt[blockIdx.x * E_NUM + tid] = h[tid];
}

__global__ void scan_kernel(const int* __restrict__ blk_cnt, int* __restrict__ boff,
                            int* __restrict__ tile_meta, int* __restrict__ n_tiles,
                            int* __restrict__ asg_tok, float* __restrict__ asg_wt) {
    __shared__ int s_start[E_NUM], s_cnt[E_NUM], s_pad[E_NUM];
    if (threadIdx.x == 0) {
        int run = 0, nt = 0;
        for (int e = 0; e < E_NUM; ++e) {
            int c = 0;
            for (int b = 0; b < NBLK; ++b) c += blk_cnt[b * E_NUM + e];
            const int tiles = (c + 127) >> 7;
            s_start[e] = run; s_cnt[e] = c; s_pad[e] = tiles << 7;
            for (int j = 0; j < tiles; ++j) {
                tile_meta[nt * 2] = e;
                tile_meta[nt * 2 + 1] = run + j * 128;
                ++nt;
            }
            int r = run;
            for (int b = 0; b < NBLK; ++b) { boff[b * E_NUM + e] = r; r += blk_cnt[b * E_NUM + e]; }
            run += tiles << 7;
        }
        *n_tiles = nt;
    }
    __syncthreads();
    for (int e = 0; e < E_NUM; ++e)
        for (int j = s_cnt[e] + threadIdx.x; j < s_pad[e]; j += 256) {
            asg_tok[s_start[e] + j] = -1;
            asg_wt[s_start[e] + j] = 0.f;
        }
}

__global__ void scatter_kernel(const int* __restrict__ tok_e, const float* __restrict__ tok_w,
                               const int* __restrict__ boff, int* __restrict__ asg_tok,
                               float* __restrict__ asg_wt, int* __restrict__ tok_slot) {
    __shared__ int wcnt[4][E_NUM];
    const int tid = threadIdx.x;
    const int lane = tid & 63;
    const int w = tid >> 6;
    const int i = blockIdx.x * 256 + tid;
    const int e = tok_e[i];
    const unsigned long long lt = (1ULL << lane) - 1ULL;
    int myrank = 0;
#pragma unroll
    for (int eq = 0; eq < E_NUM; ++eq) {
        const unsigned long long m = __ballot(e == eq);
        if (e == eq) myrank = __popcll(m & lt);
        if (lane == 0) wcnt[w][eq] = __popcll(m);
    }
    __syncthreads();
    int base = 0;
    for (int w2 = 0; w2 < w; ++w2) base += wcnt[w2][e];
    const int g = boff[blockIdx.x * E_NUM + e] + base + myrank;
    asg_tok[g] = i >> 1;
    asg_wt[g] = tok_w[i];
    tok_slot[i] = g;
}

// LDS swizzle (BK=64, 8 chunks of 8 bf16 per row): chunk ch of row r lives at
// slot = ch ^ (r&7). Fragment reads hit each bank exactly 2x per phase (free).

// ---------------- grouped GEMM1 (dual-acc GLU, BK=64) ----------------
__global__ __launch_bounds__(256, 3)
void gemm1_glu(const bf16_t* __restrict__ X, const bf16_t* __restrict__ W1all,
               const bf16_t* __restrict__ V1all, const int* __restrict__ asg_tok,
               const float* __restrict__ asg_wt, const int* __restrict__ tile_meta,
               const int* __restrict__ n_tiles, bf16_t* __restrict__ Hmid) {
    const int tile = blockIdx.x;
    if (tile >= *n_tiles) return;
    const int e = tile_meta[tile * 2];
    const int row0 = tile_meta[tile * 2 + 1];
    const bf16_t* W1 = W1all + (size_t)e * F_DIM * H_DIM;
    const bf16_t* V1 = V1all + (size_t)e * F_DIM * H_DIM;

    __shared__ __attribute__((aligned(16))) bf16_t As[128 * 64];
    __shared__ __attribute__((aligned(16))) bf16_t B1s[128 * 64];
    __shared__ __attribute__((aligned(16))) bf16_t B2s[128 * 64];
    const int tid = threadIdx.x;
    const int lane = tid & 63;
    const int wave = tid >> 6;
    const int n0 = blockIdx.y * 128;
    const int wm = (wave >> 1) * 64;
    const int wn = (wave & 1) * 64;
    const int fr = lane & 15;
    const int q = lane >> 4;

    floatx4 acc1[4][4], acc2[4][4];
    const floatx4 zero = {0.f, 0.f, 0.f, 0.f};
#pragma unroll
    for (int a = 0; a < 4; ++a)
#pragma unroll
        for (int b = 0; b < 4; ++b) { acc1[a][b] = zero; acc2[a][b] = zero; }

    // staging: call i covers rows i*32 + (tid>>3); slot = tid&7; global chunk = slot ^ (row&7)
    const int srow_lo = tid >> 3;                       // 0..31
    const int ch = (tid & 7) ^ (srow_lo & 7);           // global chunk (invariant over i)
    const int scc = ch * 8;                             // elem col offset
    const int ldsb = wave * 1024;                       // wave-uniform dest base (bytes)

    const bf16_t* ap[4]; const bf16_t* b1p[4]; const bf16_t* b2p[4];
#pragma unroll
    for (int i = 0; i < 4; ++i) {
        const int r = i * 32 + srow_lo;
        int t = asg_tok[row0 + r]; if (t < 0) t = 0;
        ap[i]  = X  + (size_t)t * H_DIM + scc;
        b1p[i] = W1 + (size_t)(n0 + r) * H_DIM + scc;
        b2p[i] = V1 + (size_t)(n0 + r) * H_DIM + scc;
    }

    for (int k0 = 0; k0 < H_DIM; k0 += 64) {
#pragma unroll
        for (int i = 0; i < 4; ++i) async_copy16(ap[i] + k0,  (char*)As  + i * 4096 + ldsb);
#pragma unroll
        for (int i = 0; i < 4; ++i) async_copy16(b1p[i] + k0, (char*)B1s + i * 4096 + ldsb);
#pragma unroll
        for (int i = 0; i < 4; ++i) async_copy16(b2p[i] + k0, (char*)B2s + i * 4096 + ldsb);
        __syncthreads();

#pragma unroll
        for (int ks = 0; ks < 2; ++ks) {
            bf16x8 af[4], b1f[4], b2f[4];
#pragma unroll
            for (int mi = 0; mi < 4; ++mi) {
                const int r = wm + mi * 16 + fr;
                const int sl = (ks * 4 + q) ^ (fr & 7);
                af[mi] = *(const bf16x8*)&As[r * 64 + sl * 8];
            }
#pragma unroll
            for (int ni = 0; ni < 4; ++ni) {
                const int r = wn + ni * 16 + fr;
                const int sl = (ks * 4 + q) ^ (fr & 7);
                b1f[ni] = *(const bf16x8*)&B1s[r * 64 + sl * 8];
                b2f[ni] = *(const bf16x8*)&B2s[r * 64 + sl * 8];
            }
#pragma unroll
            for (int mi = 0; mi < 4; ++mi)
#pragma unroll
                for (int ni = 0; ni < 4; ++ni) {
                    acc1[mi][ni] = __builtin_amdgcn_mfma_f32_16x16x32_bf16(af[mi], b1f[ni], acc1[mi][ni], 0, 0, 0);
                    acc2[mi][ni] = __builtin_amdgcn_mfma_f32_16x16x32_bf16(af[mi], b2f[ni], acc2[mi][ni], 0, 0, 0);
                }
        }
        __syncthreads();
    }

    // epilogue: C layout col = lane&15, row = q*4 + reg
#pragma unroll
    for (int mi = 0; mi < 4; ++mi) {
#pragma unroll
        for (int r = 0; r < 4; ++r) {
            const int gr = row0 + wm + mi * 16 + q * 4 + r;
            const float wt = asg_wt[gr];
            bf16_t* hp = Hmid + (size_t)gr * F_DIM + n0 + wn + fr;
#pragma unroll
            for (int ni = 0; ni < 4; ++ni) {
                const float s1 = acc1[mi][ni][r];
                const float s2 = acc2[mi][ni][r];
                const float val = (s1 / (1.f + __expf(-s1))) * s2 * wt;
                hp[ni * 16] = (bf16_t)val;
            }
        }
    }
}

// ---------------- grouped GEMM2 (BK=64): oasm[g] = hmid[g] @ W2[e] ----------------
__global__ __launch_bounds__(256, 4)
void gemm2_out(const bf16_t* __restrict__ Hmid, const bf16_t* __restrict__ W2Tall,
               const int* __restrict__ tile_meta, const int* __restrict__ n_tiles,
               float* __restrict__ Oasm) {
    const int tile = blockIdx.x;
    if (tile >= *n_tiles) return;
    const int e = tile_meta[tile * 2];
    const int row0 = tile_meta[tile * 2 + 1];
    const bf16_t* W2T = W2Tall + (size_t)e * H_DIM * F_DIM;

    __shared__ __attribute__((aligned(16))) bf16_t As[128 * 64];
    __shared__ __attribute__((aligned(16))) bf16_t Bs[128 * 64];
    const int tid = threadIdx.x;
    const int lane = tid & 63;
    const int wave = tid >> 6;
    const int n0 = blockIdx.y * 128;
    const int wm = (wave >> 1) * 64;
    const int wn = (wave & 1) * 64;
    const int fr = lane & 15;
    const int q = lane >> 4;

    floatx4 acc[4][4];
    const floatx4 zero = {0.f, 0.f, 0.f, 0.f};
#pragma unroll
    for (int a = 0; a < 4; ++a)
#pragma unroll
        for (int b = 0; b < 4; ++b) acc[a][b] = zero;

    const int srow_lo = tid >> 3;
    const int ch = (tid & 7) ^ (srow_lo & 7);
    const int scc = ch * 8;
    const int ldsb = wave * 1024;

    const bf16_t* ap[4]; const bf16_t* bp[4];
#pragma unroll
    for (int i = 0; i < 4; ++i) {
        const int r = i * 32 + srow_lo;
        ap[i] = Hmid + (size_t)(row0 + r) * F_DIM + scc;
        bp[i] = W2T  + (size_t)(n0 + r) * F_DIM + scc;
    }

    for (int k0 = 0; k0 < F_DIM; k0 += 64) {
#pragma unroll
        for (int i = 0; i < 4; ++i) async_copy16(ap[i] + k0, (char*)As + i * 4096 + ldsb);
#pragma unroll
        for (int i = 0; i < 4; ++i) async_copy16(bp[i] + k0, (char*)Bs + i * 4096 + ldsb);
        __syncthreads();

#pragma unroll
        for (int ks = 0; ks < 2; ++ks) {
            bf16x8 af[4], bf[4];
#pragma unroll
            for (int mi = 0; mi < 4; ++mi) {
                const int r = wm + mi * 16 + fr;
                const int sl = (ks * 4 + q) ^ (fr & 7);
                af[mi] = *(const bf16x8*)&As[r * 64 + sl * 8];
            }
#pragma unroll
            for (int ni = 0; ni < 4; ++ni) {
                const int r = wn + ni * 16 + fr;
                const int sl = (ks * 4 + q) ^ (fr & 7);
                bf[ni] = *(const bf16x8*)&Bs[r * 64 + sl * 8];
            }
#pragma unroll
            for (int mi = 0; mi < 4; ++mi)
#pragma unroll
                for (int ni = 0; ni < 4; ++ni)
                    acc[mi][ni] = __builtin_amdgcn_mfma_f32_16x16x32_bf16(af[mi], bf[ni], acc[mi][ni], 0, 0, 0);
        }
        __syncthreads();
    }

#pragma unroll
    for (int mi = 0; mi < 4; ++mi) {
#pragma unroll
        for (int r = 0; r < 4; ++r) {
            const int gr = row0 + wm + mi * 16 + q * 4 + r;
            float* op = Oasm + (size_t)gr * H_DIM + n0 + wn + fr;
#pragma unroll
            for (int ni = 0; ni < 4; ++ni)
                op[ni * 16] = acc[mi][ni][r];
        }
    }
}

// ---------------- combine: out[t] = oasm[slot0(t)] + oasm[slot1(t)] ----------------
__global__ void combine_kernel(const float* __restrict__ Oasm, const int* __restrict__ tok_slot,
                               float* __restrict__ Out) {
    const int t = blockIdx.x;
    const int s0 = tok_slot[t * 2];
    const int s1 = tok_slot[t * 2 + 1];
    const float4 v0 = ((const float4*)(Oasm + (size_t)s0 * H_DIM))[threadIdx.x];
    const float4 v1 = ((const float4*)(Oasm + (size_t)s1 * H_DIM))[threadIdx.x];
    float4 o; o.x = v0.x + v1.x; o.y = v0.y + v1.y; o.z = v0.z + v1.z; o.w = v0.w + v1.w;
    ((float4*)(Out + (size_t)t * H_DIM))[threadIdx.x] = o;
}

extern "C" void kernel_launch(void* const* d_in, const int* in_sizes, int n_in,
                              void* d_out, int out_size, void* d_ws, size_t ws_size,
                              hipStream_t stream) {
    const float* x  = (const float*)d_in[0];   // [T, H] fp32
    const float* rw = (const float*)d_in[1];   // [E, H] fp32
    const float* w1 = (const float*)d_in[2];   // [E, F, H] fp32
    const float* v1 = (const float*)d_in[3];   // [E, F, H] fp32
    const float* w2 = (const float*)d_in[4];   // [E, F, H] fp32
    float* out = (float*)d_out;                // [T, H] fp32

    // workspace layout. Phase-1 live: xb, w1b, v1b, hmid.
    // Phase-2 live: w2t (aliases xb+w1b head), oasm (aliases w1b tail+v1b), hmid.
    char* ws = (char*)d_ws;
    const size_t MB = 1024 * 1024;
    bf16_t* xb   = (bf16_t*)(ws + 0);          // 16 MiB [0, 16)
    bf16_t* w1b  = (bf16_t*)(ws + 16 * MB);    // 56 MiB [16, 72)
    bf16_t* v1b  = (bf16_t*)(ws + 72 * MB);    // 56 MiB [72, 128)
    bf16_t* hmid = (bf16_t*)(ws + 128 * MB);   // 119 MiB [128, ~247)
    bf16_t* w2t  = (bf16_t*)(ws + 0);          // 56 MiB [0, 56)   (after gemm1)
    float*  oasm = (float*)(ws + 56 * MB);     // 68 MiB [56, 124) (after gemm1)
    char* meta = ws + 128 * MB + (size_t)MAX_ROWS * F_DIM * 2;
    int*   asg_tok  = (int*)meta;                meta += MAX_ROWS * 4;
    float* asg_wt   = (float*)meta;              meta += MAX_ROWS * 4;
    int*   tok_slot = (int*)meta;                meta += NASG * 4;
    int*   tok_e    = (int*)meta;                meta += NASG * 4;
    float* tok_w    = (float*)meta;              meta += NASG * 4;
    int*   tile_meta = (int*)meta;               meta += MAX_TILES * 2 * 4;
    int*   n_tiles   = (int*)meta;               meta += 16;
    int*   blk_cnt   = (int*)meta;               meta += NBLK * E_NUM * 4;
    int*   boff      = (int*)meta;               meta += NBLK * E_NUM * 4;

    const int nw4 = E_NUM * F_DIM * H_DIM / 4;
    cast_f32_to_bf16<<<nw4 / 256, 256, 0, stream>>>(w1, w1b, nw4);
    cast_f32_to_bf16<<<nw4 / 256, 256, 0, stream>>>(v1, v1b, nw4);
    router_kernel<<<T_TOK / 4, 256, 0, stream>>>(x, rw, tok_e, tok_w, xb);
    hist_kernel<<<NBLK, 256, 0, stream>>>(tok_e, blk_cnt);
    scan_kernel<<<1, 256, 0, stream>>>(blk_cnt, boff, tile_meta, n_tiles, asg_tok, asg_wt);
    scatter_kernel<<<NBLK, 256, 0, stream>>>(tok_e, tok_w, boff, asg_tok, asg_wt, tok_slot);
    gemm1_glu<<<dim3(MAX_TILES, F_DIM / 128), 256, 0, stream>>>(
        xb, w1b, v1b, asg_tok, asg_wt, tile_meta, n_tiles, hmid);
    // xb/w1b/v1b dead from here; build w2t over them
    transpose_cast_w2<<<dim3(F_DIM / 32, H_DIM / 32, E_NUM), dim3(32, 8), 0, stream>>>(w2, w2t);
    gemm2_out<<<dim3(MAX_TILES, H_DIM / 128), 256, 0, stream>>>(
        hmid, w2t, tile_meta, n_tiles, oasm);
    combine_kernel<<<T_TOK, 256, 0, stream>>>(oasm, tok_slot, out);
}